// Round 5
// baseline (1070.143 us; speedup 1.0000x reference)
//
#include <hip/hip_runtime.h>

#define N_ATOMS   50000
#define N_EDGES   1600000
#define N_ANGLES  1500000

typedef unsigned short u16;
typedef _Float16 f16x8 __attribute__((ext_vector_type(8)));
typedef float    f32x4 __attribute__((ext_vector_type(4)));
typedef u16      u16x8 __attribute__((ext_vector_type(8)));

__device__ __forceinline__ float silu_f(float x) {
    return __fdividef(x, 1.0f + __expf(-x));
}
__device__ __forceinline__ u16 f2h(float x) {
    _Float16 h = (_Float16)x;
    return __builtin_bit_cast(u16, h);
}
__device__ __forceinline__ float h2f(u16 u) {
    return (float)__builtin_bit_cast(_Float16, u);
}

// ---------------------------------------------------------------------------
// Edge precompute: Rij[e] = (s/d, (s/d^2)*vec)
// ---------------------------------------------------------------------------
__global__ __launch_bounds__(256) void edge_kernel(
    const float* __restrict__ distances, const float* __restrict__ sw,
    const float* __restrict__ vec, float4* __restrict__ Rij)
{
    int e = (int)blockIdx.x * 256 + (int)threadIdx.x;
    if (e >= N_EDGES) return;
    const float d   = distances[e];
    const float s   = sw[e];
    const float inv = 1.0f / d;
    const float sij = s * inv;
    const float c   = sij * inv;
    Rij[e] = make_float4(sij, c*vec[3*e+0], c*vec[3*e+1], c*vec[3*e+2]);
}

// ---------------------------------------------------------------------------
// Prep: WTl[n][k] = f16(Wl[k][n]);  base_tab[s*16+d][j] = W0[1+s][j]+W0[17+d][j]+b0[j]
// ---------------------------------------------------------------------------
__global__ __launch_bounds__(256) void prep_kernel(
    const float* __restrict__ W0, const float* __restrict__ b0,
    const float* __restrict__ W1, const float* __restrict__ W2,
    const float* __restrict__ W3,
    u16* __restrict__ WT1, u16* __restrict__ WT2, u16* __restrict__ WT3,
    float* __restrict__ base_tab)
{
    int t = (int)blockIdx.x * 256 + (int)threadIdx.x;
    if (t < 3 * 4096) {
        int l = t >> 12, e = t & 4095, n = e >> 6, k = e & 63;
        const float* W = (l == 0) ? W1 : (l == 1) ? W2 : W3;
        u16* WT        = (l == 0) ? WT1 : (l == 1) ? WT2 : WT3;
        WT[n*64 + k] = f2h(W[k*64 + n]);
    }
    int u = t - 3 * 4096;
    if (u >= 0 && u < 256 * 64) {
        int sd = u >> 6, j = u & 63, s = sd >> 4, d = sd & 15;
        base_tab[u] = W0[(1+s)*64 + j] + W0[(17+d)*64 + j] + b0[j];
    }
}

// ---------------------------------------------------------------------------
// CSR build: histogram -> single-block scan -> fused gather+scatter
// ---------------------------------------------------------------------------
__global__ __launch_bounds__(256) void hist_kernel(
    const int* __restrict__ a_ca, int* __restrict__ cnt)
{
    int i = (int)blockIdx.x * 256 + (int)threadIdx.x;
    if (i < N_ANGLES) atomicAdd(&cnt[a_ca[i]], 1);
}

__global__ __launch_bounds__(1024) void scan_kernel(
    const int* __restrict__ cnt, int* __restrict__ cursor)
{
    __shared__ int part[1024];
    const int tid = (int)threadIdx.x;
    const int CH = 49;
    const int base = tid * CH;
    int s = 0;
    for (int k = 0; k < CH; ++k) {
        int idx = base + k;
        if (idx < N_ATOMS) s += cnt[idx];
    }
    part[tid] = s;
    __syncthreads();
    for (int off = 1; off < 1024; off <<= 1) {
        int v = (tid >= off) ? part[tid - off] : 0;
        __syncthreads();
        part[tid] += v;
        __syncthreads();
    }
    int run = (tid == 0) ? 0 : part[tid - 1];
    for (int k = 0; k < CH; ++k) {
        int idx = base + k;
        if (idx < N_ATOMS) { cursor[idx] = run; run += cnt[idx]; }
    }
}

// All random gathers live HERE (high-occupancy, latency hidden by TLP).
// Writes a packed, atom-sorted 16B record per angle: {theta, pair, ca, 0}.
__global__ __launch_bounds__(256) void scatter_kernel(
    const int* __restrict__ a_src, const int* __restrict__ a_dst,
    const int* __restrict__ a_ca, const float4* __restrict__ Rij,
    const int* __restrict__ edge_dst, const int* __restrict__ species,
    int* __restrict__ cursor, float4* __restrict__ rec)
{
    int i = (int)blockIdx.x * 256 + (int)threadIdx.x;
    if (i >= N_ANGLES) return;
    const int se = a_src[i], de = a_dst[i], ca = a_ca[i];
    const float4 Rs = Rij[se], Rd = Rij[de];
    const float theta = Rs.x*Rd.x + Rs.y*Rd.y + Rs.z*Rd.z + Rs.w*Rd.w;
    const int ssp = species[edge_dst[se]];
    const int dsp = species[edge_dst[de]];
    const int pos = atomicAdd(&cursor[ca], 1);
    rec[pos] = make_float4(theta, __int_as_float(ssp*16 + dsp),
                           __int_as_float(ca), 0.0f);
}

// ---------------------------------------------------------------------------
// MFMA helpers — fully static indexing (no runtime-selected acc reference;
// R4's runtime reference sent accumulators to scratch: +97 MB WRITE_SIZE).
// LDS act tile [64 rows][64 cols] f16, XOR-swizzled at 16B granularity:
// u16 index = row*64 + (col ^ ((row&7)<<3)).
// ---------------------------------------------------------------------------
__device__ __forceinline__ void dense_mfma(const u16* __restrict__ strip,
    const u16* __restrict__ WT, int r15, int g4, f32x4 acc[4][4])
{
    #pragma unroll
    for (int kt = 0; kt < 2; ++kt) {
        f16x8 A[4], B[4];
        #pragma unroll
        for (int mt = 0; mt < 4; ++mt) {
            int row = mt*16 + r15;
            int col = (kt*32 + g4*8) ^ ((row & 7) << 3);
            A[mt] = *(const f16x8*)&strip[row*64 + col];
        }
        #pragma unroll
        for (int nt = 0; nt < 4; ++nt)
            B[nt] = *(const f16x8*)&WT[(nt*16 + r15)*64 + kt*32 + g4*8];
        #pragma unroll
        for (int mt = 0; mt < 4; ++mt) {
            #pragma unroll
            for (int nt = 0; nt < 4; ++nt)
                acc[mt][nt] = __builtin_amdgcn_mfma_f32_16x16x32_f16(
                    A[mt], B[nt], acc[mt][nt], 0, 0, 0);
        }
    }
}

__device__ __forceinline__ void act_store(u16* __restrict__ strip,
    const float* __restrict__ bias, int r15, int g4, f32x4 acc[4][4])
{
    float bn[4];
    #pragma unroll
    for (int nt = 0; nt < 4; ++nt) bn[nt] = bias[nt*16 + r15];
    #pragma unroll
    for (int mt = 0; mt < 4; ++mt) {
        #pragma unroll
        for (int r = 0; r < 4; ++r) {
            int row = mt*16 + g4*4 + r;
            int rsw = (row & 7) << 3;
            #pragma unroll
            for (int nt = 0; nt < 4; ++nt)
                strip[row*64 + ((nt*16 + r15) ^ rsw)] =
                    f2h(silu_f(acc[mt][nt][r] + bn[nt]));
        }
    }
}

// ---------------------------------------------------------------------------
// Angle kernel: 4 waves x 64-angle strips; input = ONE coalesced record stream.
// MLP phase barrier-free (wave-private LDS strips). L3 runs twice into accG
// (init 2*b3). Scatter: CSR segmented reduction with u16x8 vector reads.
// __launch_bounds__(256,3): cap VGPR ~170 -> 3 waves/SIMD (was 2 at 184).
// ---------------------------------------------------------------------------
__global__ __launch_bounds__(256, 3) void angle_kernel(
    const float4* __restrict__ rec,
    const float* __restrict__ W0, const float* __restrict__ base_tab,
    const u16* __restrict__ WT1, const u16* __restrict__ WT2,
    const u16* __restrict__ WT3,
    const float* __restrict__ b1, const float* __restrict__ b2,
    const float* __restrict__ b3,
    float* __restrict__ out)
{
    __shared__ __align__(16) u16 act[256 * 64];   // 32 KB
    __shared__ float theta_s[256];
    __shared__ int   atomv[256];
    __shared__ int   seg_start[256];
    __shared__ int   nseg;

    const int tid  = (int)threadIdx.x;
    const int lane = tid & 63;
    const int wv   = tid >> 6;
    const int r15  = lane & 15;
    const int g4   = lane >> 4;

    const int i = (int)blockIdx.x * 256 + tid;
    const bool active = (i < N_ANGLES);
    const float4 rv = rec[active ? i : 0];

    const float theta = active ? rv.x : 0.0f;
    const int   pair  = __float_as_int(rv.y);
    const int   ca    = active ? __float_as_int(rv.z) : -1;

    if (tid == 0) nseg = 0;
    atomv[tid]   = ca;
    theta_s[tid] = theta;

    u16* strip = act + wv * 4096;

    // persistent G accumulator: G = h2a@W3 + h2b@W3 + 2*b3
    f32x4 accG[4][4];
    #pragma unroll
    for (int nt = 0; nt < 4; ++nt) {
        float bv = 2.0f * b3[nt*16 + r15];
        #pragma unroll
        for (int mt = 0; mt < 4; ++mt) accG[mt][nt] = {bv, bv, bv, bv};
    }

    #pragma unroll 1
    for (int m = 0; m < 2; ++m) {
        // ---- layer 0 (one-hot collapsed): thread's own row = lane
        {
            const int p = m ? (((pair & 15) << 4) | (pair >> 4)) : pair;
            const float4* bs4 = (const float4*)(base_tab + p*64);
            const float4* w04 = (const float4*)W0;     // row 0, wave-uniform
            const int rsw = (lane & 7) << 3;
            #pragma unroll
            for (int c = 0; c < 8; ++c) {
                float4 bl = bs4[2*c], bh = bs4[2*c+1];
                float4 wl = w04[2*c], wh = w04[2*c+1];
                u16x8 hv;
                hv[0] = f2h(silu_f(fmaf(theta, wl.x, bl.x)));
                hv[1] = f2h(silu_f(fmaf(theta, wl.y, bl.y)));
                hv[2] = f2h(silu_f(fmaf(theta, wl.z, bl.z)));
                hv[3] = f2h(silu_f(fmaf(theta, wl.w, bl.w)));
                hv[4] = f2h(silu_f(fmaf(theta, wh.x, bh.x)));
                hv[5] = f2h(silu_f(fmaf(theta, wh.y, bh.y)));
                hv[6] = f2h(silu_f(fmaf(theta, wh.z, bh.z)));
                hv[7] = f2h(silu_f(fmaf(theta, wh.w, bh.w)));
                *(u16x8*)&strip[lane*64 + ((c*8) ^ rsw)] = hv;
            }
        }

        // ---- layer 1 (static)
        {
            f32x4 acc[4][4];
            #pragma unroll
            for (int mt = 0; mt < 4; ++mt)
                #pragma unroll
                for (int nt = 0; nt < 4; ++nt) acc[mt][nt] = {0.f,0.f,0.f,0.f};
            dense_mfma(strip, WT1, r15, g4, acc);
            act_store(strip, b1, r15, g4, acc);
        }
        // ---- layer 2 (static)
        {
            f32x4 acc[4][4];
            #pragma unroll
            for (int mt = 0; mt < 4; ++mt)
                #pragma unroll
                for (int nt = 0; nt < 4; ++nt) acc[mt][nt] = {0.f,0.f,0.f,0.f};
            dense_mfma(strip, WT2, r15, g4, acc);
            act_store(strip, b2, r15, g4, acc);
        }
        // ---- layer 3: accumulate directly into persistent accG (static)
        dense_mfma(strip, WT3, r15, g4, accG);
    }

    // write g*theta (f16) into act, now a [256 angles][64 feat] red buffer
    #pragma unroll
    for (int mt = 0; mt < 4; ++mt) {
        #pragma unroll
        for (int r = 0; r < 4; ++r) {
            int row = mt*16 + g4*4 + r;
            float th = theta_s[wv*64 + row];
            int rsw = (row & 7) << 3;
            #pragma unroll
            for (int nt = 0; nt < 4; ++nt)
                strip[row*64 + ((nt*16 + r15) ^ rsw)] = f2h(accG[mt][nt][r] * th);
        }
    }
    __syncthreads();

    // segment heads
    if (active && (tid == 0 || atomv[tid] != atomv[tid-1]))
        seg_start[atomicAdd(&nseg, 1)] = tid;
    __syncthreads();

    // CSR segmented reduction, vectorized: task = (segment, 8-feature chunk)
    const int NS = nseg;
    for (int w = tid; w < NS * 8; w += 256) {
        const int s  = w >> 3;
        const int j0 = (w & 7) * 8;
        const int st = seg_start[s];
        const int atom = atomv[st];
        float sum[8] = {0,0,0,0,0,0,0,0};
        for (int t = st; t < 256 && atomv[t] == atom; ++t) {
            u16x8 v = *(const u16x8*)&act[t*64 + (j0 ^ ((t & 7) << 3))];
            #pragma unroll
            for (int q = 0; q < 8; ++q) sum[q] += h2f(v[q]);
        }
        float* op = out + (size_t)atom * 64 + j0;
        #pragma unroll
        for (int q = 0; q < 8; ++q) atomicAdd(op + q, sum[q]);
    }
}

extern "C" void kernel_launch(void* const* d_in, const int* in_sizes, int n_in,
                              void* d_out, int out_size, void* d_ws, size_t ws_size,
                              hipStream_t stream) {
    const int*   species   = (const int*)  d_in[0];
    const int*   edge_dst  = (const int*)  d_in[1];
    const float* distances = (const float*)d_in[2];
    const float* sw        = (const float*)d_in[3];
    const float* vec       = (const float*)d_in[4];
    const int*   a_src     = (const int*)  d_in[5];
    const int*   a_dst     = (const int*)  d_in[6];
    const int*   a_ca      = (const int*)  d_in[7];
    const float* W0 = (const float*)d_in[8];
    const float* b0 = (const float*)d_in[9];
    const float* W1 = (const float*)d_in[10];
    const float* b1 = (const float*)d_in[11];
    const float* W2 = (const float*)d_in[12];
    const float* b2 = (const float*)d_in[13];
    const float* W3 = (const float*)d_in[14];
    const float* b3 = (const float*)d_in[15];
    float* out = (float*)d_out;

    // ws: Rij(25.6MB) | cnt | cursor | rec(24MB) | WT1/2/3 | base_tab  (~50MB)
    float4* Rij    = (float4*)d_ws;
    int*    cnt    = (int*)(Rij + N_EDGES);
    int*    cursor = cnt + N_ATOMS;
    float4* rec    = (float4*)(cursor + N_ATOMS);
    u16*    WT1    = (u16*)(rec + N_ANGLES);
    u16*    WT2    = WT1 + 4096;
    u16*    WT3    = WT2 + 4096;
    float*  base_tab = (float*)(WT3 + 4096);

    hipMemsetAsync(d_out, 0, (size_t)out_size * sizeof(float), stream);
    hipMemsetAsync(cnt, 0, (size_t)N_ATOMS * sizeof(int), stream);

    edge_kernel<<<(N_EDGES + 255) / 256, 256, 0, stream>>>(distances, sw, vec, Rij);
    prep_kernel<<<(3*4096 + 256*64 + 255) / 256, 256, 0, stream>>>(
        W0, b0, W1, W2, W3, WT1, WT2, WT3, base_tab);
    hist_kernel<<<(N_ANGLES + 255) / 256, 256, 0, stream>>>(a_ca, cnt);
    scan_kernel<<<1, 1024, 0, stream>>>(cnt, cursor);
    scatter_kernel<<<(N_ANGLES + 255) / 256, 256, 0, stream>>>(
        a_src, a_dst, a_ca, Rij, edge_dst, species, cursor, rec);

    angle_kernel<<<(N_ANGLES + 255) / 256, 256, 0, stream>>>(
        rec, W0, base_tab, WT1, WT2, WT3, b1, b2, b3, out);
}

// Round 6
// 569.054 us; speedup vs baseline: 1.8806x; 1.8806x over previous
//
#include <hip/hip_runtime.h>

#define N_ATOMS   50000
#define N_EDGES   1600000
#define N_ANGLES  1500000

// theta-table: theta = 8*sinh(u), u uniform on [-UMAX, UMAX], NT points.
// Covers |theta| <= 512 (realistic max ~150); spacing 0.038 at theta=0.
#define NT      2048
#define UMAX    4.852092f
#define H_U     0.004740686f     // 2*UMAX/(NT-1)
#define INV_HU  210.93994f       // (NT-1)/(2*UMAX)

typedef unsigned short u16;
typedef _Float16 f16x8 __attribute__((ext_vector_type(8)));
typedef float    f32x4 __attribute__((ext_vector_type(4)));
typedef u16      u16x8 __attribute__((ext_vector_type(8)));

__device__ __forceinline__ float silu_f(float x) {
    return __fdividef(x, 1.0f + __expf(-x));
}
__device__ __forceinline__ u16 f2h(float x) {
    _Float16 h = (_Float16)x;
    return __builtin_bit_cast(u16, h);
}
__device__ __forceinline__ float h2f(u16 u) {
    return (float)__builtin_bit_cast(_Float16, u);
}

// ---------------------------------------------------------------------------
// Edge precompute: Rij[e] = (s/d, (s/d^2)*vec); espec[e] = species[edge_dst[e]]
// (precomputing espec removes the dependent 2-hop gather from scatter_kernel)
// ---------------------------------------------------------------------------
__global__ __launch_bounds__(256) void edge_kernel(
    const float* __restrict__ distances, const float* __restrict__ sw,
    const float* __restrict__ vec, const int* __restrict__ edge_dst,
    const int* __restrict__ species,
    float4* __restrict__ Rij, int* __restrict__ espec)
{
    int e = (int)blockIdx.x * 256 + (int)threadIdx.x;
    if (e >= N_EDGES) return;
    const float d   = distances[e];
    const float s   = sw[e];
    const float inv = 1.0f / d;
    const float sij = s * inv;
    const float c   = sij * inv;
    Rij[e]   = make_float4(sij, c*vec[3*e+0], c*vec[3*e+1], c*vec[3*e+2]);
    espec[e] = species[edge_dst[e]];
}

// ---------------------------------------------------------------------------
// Prep: WTl[n][k] = f16(Wl[k][n]);  base_tab[s*16+d][j] = W0[1+s][j]+W0[17+d][j]+b0[j]
// ---------------------------------------------------------------------------
__global__ __launch_bounds__(256) void prep_kernel(
    const float* __restrict__ W0, const float* __restrict__ b0,
    const float* __restrict__ W1, const float* __restrict__ W2,
    const float* __restrict__ W3,
    u16* __restrict__ WT1, u16* __restrict__ WT2, u16* __restrict__ WT3,
    float* __restrict__ base_tab)
{
    int t = (int)blockIdx.x * 256 + (int)threadIdx.x;
    if (t < 3 * 4096) {
        int l = t >> 12, e = t & 4095, n = e >> 6, k = e & 63;
        const float* W = (l == 0) ? W1 : (l == 1) ? W2 : W3;
        u16* WT        = (l == 0) ? WT1 : (l == 1) ? WT2 : WT3;
        WT[n*64 + k] = f2h(W[k*64 + n]);
    }
    int u = t - 3 * 4096;
    if (u >= 0 && u < 256 * 64) {
        int sd = u >> 6, j = u & 63, s = sd >> 4, d = sd & 15;
        base_tab[u] = W0[(1+s)*64 + j] + W0[(17+d)*64 + j] + b0[j];
    }
}

// ---------------------------------------------------------------------------
// CSR build: histogram -> single-block scan -> gather+scatter (packed record)
// ---------------------------------------------------------------------------
__global__ __launch_bounds__(256) void hist_kernel(
    const int* __restrict__ a_ca, int* __restrict__ cnt)
{
    int i = (int)blockIdx.x * 256 + (int)threadIdx.x;
    if (i < N_ANGLES) atomicAdd(&cnt[a_ca[i]], 1);
}

__global__ __launch_bounds__(1024) void scan_kernel(
    const int* __restrict__ cnt, int* __restrict__ cursor)
{
    __shared__ int part[1024];
    const int tid = (int)threadIdx.x;
    const int CH = 49;
    const int base = tid * CH;
    int s = 0;
    for (int k = 0; k < CH; ++k) {
        int idx = base + k;
        if (idx < N_ATOMS) s += cnt[idx];
    }
    part[tid] = s;
    __syncthreads();
    for (int off = 1; off < 1024; off <<= 1) {
        int v = (tid >= off) ? part[tid - off] : 0;
        __syncthreads();
        part[tid] += v;
        __syncthreads();
    }
    int run = (tid == 0) ? 0 : part[tid - 1];
    for (int k = 0; k < CH; ++k) {
        int idx = base + k;
        if (idx < N_ATOMS) { cursor[idx] = run; run += cnt[idx]; }
    }
}

// Writes atom-sorted 16B record per angle: {theta, tri-pair-id, ca, 0}.
// tri id (s<=d canonical, G symmetric in (s,d)): pid = 16s - s(s-1)/2 + (d-s).
__global__ __launch_bounds__(256) void scatter_kernel(
    const int* __restrict__ a_src, const int* __restrict__ a_dst,
    const int* __restrict__ a_ca, const float4* __restrict__ Rij,
    const int* __restrict__ espec,
    int* __restrict__ cursor, float4* __restrict__ rec)
{
    int i = (int)blockIdx.x * 256 + (int)threadIdx.x;
    if (i >= N_ANGLES) return;
    const int se = a_src[i], de = a_dst[i], ca = a_ca[i];
    const float4 Rs = Rij[se], Rd = Rij[de];
    const float theta = Rs.x*Rd.x + Rs.y*Rd.y + Rs.z*Rd.z + Rs.w*Rd.w;
    const int s1 = espec[se], s2 = espec[de];
    const int s = min(s1, s2), d = max(s1, s2);
    const int pid = s*16 - (s*(s-1))/2 + (d - s);
    const int pos = atomicAdd(&cursor[ca], 1);
    rec[pos] = make_float4(theta, __int_as_float(pid),
                           __int_as_float(ca), 0.0f);
}

// ---------------------------------------------------------------------------
// MFMA helpers (static indexing; LDS tile u16 index = row*64 + (col^((row&7)<<3)))
// ---------------------------------------------------------------------------
__device__ __forceinline__ void dense_mfma(const u16* __restrict__ strip,
    const u16* __restrict__ WT, int r15, int g4, f32x4 acc[4][4])
{
    #pragma unroll
    for (int kt = 0; kt < 2; ++kt) {
        f16x8 A[4], B[4];
        #pragma unroll
        for (int mt = 0; mt < 4; ++mt) {
            int row = mt*16 + r15;
            int col = (kt*32 + g4*8) ^ ((row & 7) << 3);
            A[mt] = *(const f16x8*)&strip[row*64 + col];
        }
        #pragma unroll
        for (int nt = 0; nt < 4; ++nt)
            B[nt] = *(const f16x8*)&WT[(nt*16 + r15)*64 + kt*32 + g4*8];
        #pragma unroll
        for (int mt = 0; mt < 4; ++mt) {
            #pragma unroll
            for (int nt = 0; nt < 4; ++nt)
                acc[mt][nt] = __builtin_amdgcn_mfma_f32_16x16x32_f16(
                    A[mt], B[nt], acc[mt][nt], 0, 0, 0);
        }
    }
}

__device__ __forceinline__ void act_store(u16* __restrict__ strip,
    const float* __restrict__ bias, int r15, int g4, f32x4 acc[4][4])
{
    float bn[4];
    #pragma unroll
    for (int nt = 0; nt < 4; ++nt) bn[nt] = bias[nt*16 + r15];
    #pragma unroll
    for (int mt = 0; mt < 4; ++mt) {
        #pragma unroll
        for (int r = 0; r < 4; ++r) {
            int row = mt*16 + g4*4 + r;
            int rsw = (row & 7) << 3;
            #pragma unroll
            for (int nt = 0; nt < 4; ++nt)
                strip[row*64 + ((nt*16 + r15) ^ rsw)] =
                    f2h(silu_f(acc[mt][nt][r] + bn[nt]));
        }
    }
}

// ---------------------------------------------------------------------------
// Table build: grid = 136 pairs x 8 theta-chunks. Block = 4 waves x 64 rows.
// Row (theta grid point) idx = chunk*256 + tid; theta = 8*sinh(-UMAX + idx*H_U).
// MLP identical to R3/R5 (one-hot collapse, shared W3, static accG).
// Writes G (NOT *theta) as f16: T[pid][idx][0:64].
// ---------------------------------------------------------------------------
__global__ __launch_bounds__(256) void build_kernel(
    const float* __restrict__ W0, const float* __restrict__ base_tab,
    const u16* __restrict__ WT1, const u16* __restrict__ WT2,
    const u16* __restrict__ WT3,
    const float* __restrict__ b1, const float* __restrict__ b2,
    const float* __restrict__ b3,
    u16* __restrict__ T)
{
    __shared__ __align__(16) u16 act[256 * 64];   // 32 KB

    const int tid  = (int)threadIdx.x;
    const int lane = tid & 63;
    const int wv   = tid >> 6;
    const int r15  = lane & 15;
    const int g4   = lane >> 4;

    const int pid   = (int)blockIdx.x >> 3;
    const int chunk = (int)blockIdx.x & 7;
    // decode tri id -> (s, d), s <= d
    int s = 0, rem = pid;
    while (rem >= 16 - s) { rem -= 16 - s; ++s; }
    const int d = s + rem;

    const int idx = chunk * 256 + tid;              // theta grid index
    const float u  = fmaf((float)idx, H_U, -UMAX);
    const float eu = __expf(u);
    const float theta = 4.0f * (eu - __frcp_rn(eu)); // 8*sinh(u)

    u16* strip = act + wv * 4096;

    f32x4 accG[4][4];
    #pragma unroll
    for (int nt = 0; nt < 4; ++nt) {
        float bv = 2.0f * b3[nt*16 + r15];
        #pragma unroll
        for (int mt = 0; mt < 4; ++mt) accG[mt][nt] = {bv, bv, bv, bv};
    }

    #pragma unroll 1
    for (int m = 0; m < 2; ++m) {
        // layer 0 (one-hot collapsed)
        {
            const int p = m ? (d*16 + s) : (s*16 + d);
            const float4* bs4 = (const float4*)(base_tab + p*64);
            const float4* w04 = (const float4*)W0;
            const int rsw = (lane & 7) << 3;
            #pragma unroll
            for (int c = 0; c < 8; ++c) {
                float4 bl = bs4[2*c], bh = bs4[2*c+1];
                float4 wl = w04[2*c], wh = w04[2*c+1];
                u16x8 hv;
                hv[0] = f2h(silu_f(fmaf(theta, wl.x, bl.x)));
                hv[1] = f2h(silu_f(fmaf(theta, wl.y, bl.y)));
                hv[2] = f2h(silu_f(fmaf(theta, wl.z, bl.z)));
                hv[3] = f2h(silu_f(fmaf(theta, wl.w, bl.w)));
                hv[4] = f2h(silu_f(fmaf(theta, wh.x, bh.x)));
                hv[5] = f2h(silu_f(fmaf(theta, wh.y, bh.y)));
                hv[6] = f2h(silu_f(fmaf(theta, wh.z, bh.z)));
                hv[7] = f2h(silu_f(fmaf(theta, wh.w, bh.w)));
                *(u16x8*)&strip[lane*64 + ((c*8) ^ rsw)] = hv;
            }
        }
        // layer 1
        {
            f32x4 acc[4][4];
            #pragma unroll
            for (int mt = 0; mt < 4; ++mt)
                #pragma unroll
                for (int nt = 0; nt < 4; ++nt) acc[mt][nt] = {0.f,0.f,0.f,0.f};
            dense_mfma(strip, WT1, r15, g4, acc);
            act_store(strip, b1, r15, g4, acc);
        }
        // layer 2
        {
            f32x4 acc[4][4];
            #pragma unroll
            for (int mt = 0; mt < 4; ++mt)
                #pragma unroll
                for (int nt = 0; nt < 4; ++nt) acc[mt][nt] = {0.f,0.f,0.f,0.f};
            dense_mfma(strip, WT2, r15, g4, acc);
            act_store(strip, b2, r15, g4, acc);
        }
        // layer 3 -> persistent accG
        dense_mfma(strip, WT3, r15, g4, accG);
    }

    // stash G (f16) into act rows
    #pragma unroll
    for (int mt = 0; mt < 4; ++mt) {
        #pragma unroll
        for (int r = 0; r < 4; ++r) {
            int row = mt*16 + g4*4 + r;
            int rsw = (row & 7) << 3;
            #pragma unroll
            for (int nt = 0; nt < 4; ++nt)
                strip[row*64 + ((nt*16 + r15) ^ rsw)] = f2h(accG[mt][nt][r]);
        }
    }
    __syncthreads();

    // coalesced copy-out: thread tid owns act row tid -> T[pid][idx]
    u16* dst = T + ((size_t)pid * NT + (size_t)idx) * 64;
    const int rsw = (tid & 7) << 3;
    #pragma unroll
    for (int c = 0; c < 8; ++c)
        *(u16x8*)(dst + c*8) = *(const u16x8*)&act[tid*64 + ((c*8) ^ rsw)];
}

// ---------------------------------------------------------------------------
// Lookup + segmented reduction: per angle, lerp T[pid] at theta, * theta,
// then CSR segmented sum -> one atomicAdd per (segment, 8-feature chunk).
// ---------------------------------------------------------------------------
__global__ __launch_bounds__(256) void lookup_kernel(
    const float4* __restrict__ rec, const u16* __restrict__ T,
    float* __restrict__ out)
{
    __shared__ __align__(16) u16 red[256 * 64];   // 32 KB, [t][j^((t&7)<<3)]
    __shared__ int atomv[256];
    __shared__ int seg_start[256];
    __shared__ int nseg;

    const int tid = (int)threadIdx.x;
    const int i = (int)blockIdx.x * 256 + tid;
    const bool active = (i < N_ANGLES);
    const float4 rv = rec[active ? i : 0];

    const float theta = active ? rv.x : 0.0f;
    const int   pid   = __float_as_int(rv.y);
    const int   ca    = active ? __float_as_int(rv.z) : -1;

    if (tid == 0) nseg = 0;
    atomv[tid] = ca;

    // u = asinh(theta/8); t = (u+UMAX)/h_u; lerp rows i0, i0+1
    const float x  = theta * 0.125f;
    const float ax = fabsf(x);
    float uu = __logf(ax + __fsqrt_rn(fmaf(ax, ax, 1.0f)));
    uu = copysignf(uu, x);
    float tt = fminf(fmaxf(fmaf(uu, INV_HU, UMAX * INV_HU), 0.0f),
                     (float)NT - 1.001f);
    const int   i0 = (int)tt;
    const float fr = tt - (float)i0;

    const u16* __restrict__ r0 = T + ((size_t)pid * NT + (size_t)i0) * 64;
    const int rsw = (tid & 7) << 3;
    #pragma unroll
    for (int c = 0; c < 8; ++c) {
        u16x8 va = *(const u16x8*)(r0 + c*8);
        u16x8 vb = *(const u16x8*)(r0 + 64 + c*8);
        u16x8 o;
        #pragma unroll
        for (int q = 0; q < 8; ++q) {
            float ga = h2f(va[q]);
            float g  = fmaf(fr, h2f(vb[q]) - ga, ga);
            o[q] = f2h(g * theta);
        }
        *(u16x8*)&red[tid*64 + ((c*8) ^ rsw)] = o;
    }
    __syncthreads();

    if (active && (tid == 0 || atomv[tid] != atomv[tid-1]))
        seg_start[atomicAdd(&nseg, 1)] = tid;
    __syncthreads();

    const int NS = nseg;
    for (int w = tid; w < NS * 8; w += 256) {
        const int s  = w >> 3;
        const int j0 = (w & 7) * 8;
        const int st = seg_start[s];
        const int atom = atomv[st];
        float sum[8] = {0,0,0,0,0,0,0,0};
        for (int t = st; t < 256 && atomv[t] == atom; ++t) {
            u16x8 v = *(const u16x8*)&red[t*64 + (j0 ^ ((t & 7) << 3))];
            #pragma unroll
            for (int q = 0; q < 8; ++q) sum[q] += h2f(v[q]);
        }
        float* op = out + (size_t)atom * 64 + j0;
        #pragma unroll
        for (int q = 0; q < 8; ++q) atomicAdd(op + q, sum[q]);
    }
}

extern "C" void kernel_launch(void* const* d_in, const int* in_sizes, int n_in,
                              void* d_out, int out_size, void* d_ws, size_t ws_size,
                              hipStream_t stream) {
    const int*   species   = (const int*)  d_in[0];
    const int*   edge_dst  = (const int*)  d_in[1];
    const float* distances = (const float*)d_in[2];
    const float* sw        = (const float*)d_in[3];
    const float* vec       = (const float*)d_in[4];
    const int*   a_src     = (const int*)  d_in[5];
    const int*   a_dst     = (const int*)  d_in[6];
    const int*   a_ca      = (const int*)  d_in[7];
    const float* W0 = (const float*)d_in[8];
    const float* b0 = (const float*)d_in[9];
    const float* W1 = (const float*)d_in[10];
    const float* b1 = (const float*)d_in[11];
    const float* W2 = (const float*)d_in[12];
    const float* b2 = (const float*)d_in[13];
    const float* W3 = (const float*)d_in[14];
    const float* b3 = (const float*)d_in[15];
    float* out = (float*)d_out;

    // ws: Rij 25.6M | espec 6.4M | cnt 0.2M | cursor 0.2M | rec 24M |
    //     WT1/2/3 24K | base_tab 64K | T 35.7M   (~92 MB, all 16B-aligned)
    float4* Rij    = (float4*)d_ws;
    int*    espec  = (int*)(Rij + N_EDGES);
    int*    cnt    = espec + N_EDGES;
    int*    cursor = cnt + N_ATOMS;
    float4* rec    = (float4*)(cursor + N_ATOMS);
    u16*    WT1    = (u16*)(rec + N_ANGLES);
    u16*    WT2    = WT1 + 4096;
    u16*    WT3    = WT2 + 4096;
    float*  base_tab = (float*)(WT3 + 4096);
    u16*    T      = (u16*)(base_tab + 256*64);

    hipMemsetAsync(d_out, 0, (size_t)out_size * sizeof(float), stream);
    hipMemsetAsync(cnt, 0, (size_t)N_ATOMS * sizeof(int), stream);

    edge_kernel<<<(N_EDGES + 255) / 256, 256, 0, stream>>>(
        distances, sw, vec, edge_dst, species, Rij, espec);
    prep_kernel<<<(3*4096 + 256*64 + 255) / 256, 256, 0, stream>>>(
        W0, b0, W1, W2, W3, WT1, WT2, WT3, base_tab);
    hist_kernel<<<(N_ANGLES + 255) / 256, 256, 0, stream>>>(a_ca, cnt);
    scan_kernel<<<1, 1024, 0, stream>>>(cnt, cursor);
    scatter_kernel<<<(N_ANGLES + 255) / 256, 256, 0, stream>>>(
        a_src, a_dst, a_ca, Rij, espec, cursor, rec);
    build_kernel<<<136 * 8, 256, 0, stream>>>(
        W0, base_tab, WT1, WT2, WT3, b1, b2, b3, T);
    lookup_kernel<<<(N_ANGLES + 255) / 256, 256, 0, stream>>>(rec, T, out);
}

// Round 7
// 401.288 us; speedup vs baseline: 2.6668x; 1.4181x over previous
//
#include <hip/hip_runtime.h>

#define N_ATOMS   50000
#define N_EDGES   1600000
#define N_ANGLES  1500000
#define SCAN_B    196            // ceil(N_ATOMS/256)

// theta-table: theta = 8*sinh(u), u uniform on [-UMAX, UMAX], NT points.
// Covers |theta| <= 512; u-spacing 0.00949 -> lerp err ~2e-3*theta (harmless).
#define NT      1024
#define UMAX    4.852092f
#define H_U     0.009486005f     // 2*UMAX/(NT-1)
#define INV_HU  105.41852f       // (NT-1)/(2*UMAX)

typedef unsigned short u16;
typedef _Float16 f16x8 __attribute__((ext_vector_type(8)));
typedef float    f32x4 __attribute__((ext_vector_type(4)));
typedef u16      u16x8 __attribute__((ext_vector_type(8)));

__device__ __forceinline__ float silu_f(float x) {
    return __fdividef(x, 1.0f + __expf(-x));
}
__device__ __forceinline__ u16 f2h(float x) {
    _Float16 h = (_Float16)x;
    return __builtin_bit_cast(u16, h);
}
__device__ __forceinline__ float h2f(u16 u) {
    return (float)__builtin_bit_cast(_Float16, u);
}

// ---------------------------------------------------------------------------
// Edge precompute: Rij[e] = (s/d, (s/d^2)*vec); espec[e] = species[edge_dst[e]]
// ---------------------------------------------------------------------------
__global__ __launch_bounds__(256) void edge_kernel(
    const float* __restrict__ distances, const float* __restrict__ sw,
    const float* __restrict__ vec, const int* __restrict__ edge_dst,
    const int* __restrict__ species,
    float4* __restrict__ Rij, int* __restrict__ espec)
{
    int e = (int)blockIdx.x * 256 + (int)threadIdx.x;
    if (e >= N_EDGES) return;
    const float d   = distances[e];
    const float s   = sw[e];
    const float inv = 1.0f / d;
    const float sij = s * inv;
    const float c   = sij * inv;
    Rij[e]   = make_float4(sij, c*vec[3*e+0], c*vec[3*e+1], c*vec[3*e+2]);
    espec[e] = species[edge_dst[e]];
}

// ---------------------------------------------------------------------------
// Prep: WTl[n][k] = f16(Wl[k][n]);  base_tab[s*16+d][j] = W0[1+s][j]+W0[17+d][j]+b0[j]
// ---------------------------------------------------------------------------
__global__ __launch_bounds__(256) void prep_kernel(
    const float* __restrict__ W0, const float* __restrict__ b0,
    const float* __restrict__ W1, const float* __restrict__ W2,
    const float* __restrict__ W3,
    u16* __restrict__ WT1, u16* __restrict__ WT2, u16* __restrict__ WT3,
    float* __restrict__ base_tab)
{
    int t = (int)blockIdx.x * 256 + (int)threadIdx.x;
    if (t < 3 * 4096) {
        int l = t >> 12, e = t & 4095, n = e >> 6, k = e & 63;
        const float* W = (l == 0) ? W1 : (l == 1) ? W2 : W3;
        u16* WT        = (l == 0) ? WT1 : (l == 1) ? WT2 : WT3;
        WT[n*64 + k] = f2h(W[k*64 + n]);
    }
    int u = t - 3 * 4096;
    if (u >= 0 && u < 256 * 64) {
        int sd = u >> 6, j = u & 63, s = sd >> 4, d = sd & 15;
        base_tab[u] = W0[(1+s)*64 + j] + W0[(17+d)*64 + j] + b0[j];
    }
}

// ---------------------------------------------------------------------------
// CSR build: histogram -> 3-stage parallel scan -> gather+scatter
// ---------------------------------------------------------------------------
__global__ __launch_bounds__(256) void hist_kernel(
    const int* __restrict__ a_ca, int* __restrict__ cnt)
{
    int i = (int)blockIdx.x * 256 + (int)threadIdx.x;
    if (i < N_ANGLES) atomicAdd(&cnt[a_ca[i]], 1);
}

__global__ __launch_bounds__(256) void scanA_kernel(
    const int* __restrict__ cnt, int* __restrict__ bsum)
{
    __shared__ int ws[4];
    const int t = (int)threadIdx.x;
    const int idx = (int)blockIdx.x * 256 + t;
    int v = (idx < N_ATOMS) ? cnt[idx] : 0;
    #pragma unroll
    for (int off = 32; off; off >>= 1) v += __shfl_down(v, off, 64);
    if ((t & 63) == 0) ws[t >> 6] = v;
    __syncthreads();
    if (t == 0) bsum[blockIdx.x] = ws[0] + ws[1] + ws[2] + ws[3];
}

__global__ __launch_bounds__(256) void scanB_kernel(
    const int* __restrict__ bsum, int* __restrict__ boff)
{
    __shared__ int sh[256];
    const int t = (int)threadIdx.x;
    int v = (t < SCAN_B) ? bsum[t] : 0;
    sh[t] = v;
    __syncthreads();
    for (int off = 1; off < 256; off <<= 1) {
        int u = (t >= off) ? sh[t - off] : 0;
        __syncthreads();
        sh[t] += u;
        __syncthreads();
    }
    if (t < SCAN_B) boff[t] = sh[t] - v;   // exclusive
}

__global__ __launch_bounds__(256) void scanC_kernel(
    const int* __restrict__ cnt, const int* __restrict__ boff,
    int* __restrict__ cursor)
{
    __shared__ int sh[256];
    const int t = (int)threadIdx.x;
    const int idx = (int)blockIdx.x * 256 + t;
    int v = (idx < N_ATOMS) ? cnt[idx] : 0;
    sh[t] = v;
    __syncthreads();
    for (int off = 1; off < 256; off <<= 1) {
        int u = (t >= off) ? sh[t - off] : 0;
        __syncthreads();
        sh[t] += u;
        __syncthreads();
    }
    if (idx < N_ATOMS) cursor[idx] = boff[blockIdx.x] + sh[t] - v;
}

// Writes atom-sorted 16B record per angle: {theta, tri-pair-id, ca, 0}.
// tri id (s<=d canonical, G symmetric in (s,d)): pid = 16s - s(s-1)/2 + (d-s).
__global__ __launch_bounds__(256) void scatter_kernel(
    const int* __restrict__ a_src, const int* __restrict__ a_dst,
    const int* __restrict__ a_ca, const float4* __restrict__ Rij,
    const int* __restrict__ espec,
    int* __restrict__ cursor, float4* __restrict__ rec)
{
    int i = (int)blockIdx.x * 256 + (int)threadIdx.x;
    if (i >= N_ANGLES) return;
    const int se = a_src[i], de = a_dst[i], ca = a_ca[i];
    const float4 Rs = Rij[se], Rd = Rij[de];
    const float theta = Rs.x*Rd.x + Rs.y*Rd.y + Rs.z*Rd.z + Rs.w*Rd.w;
    const int s1 = espec[se], s2 = espec[de];
    const int s = min(s1, s2), d = max(s1, s2);
    const int pid = s*16 - (s*(s-1))/2 + (d - s);
    const int pos = atomicAdd(&cursor[ca], 1);
    rec[pos] = make_float4(theta, __int_as_float(pid),
                           __int_as_float(ca), 0.0f);
}

// ---------------------------------------------------------------------------
// MFMA helpers (static indexing; LDS tile u16 index = row*64 + (col^((row&7)<<3)))
// ---------------------------------------------------------------------------
__device__ __forceinline__ void dense_mfma(const u16* __restrict__ strip,
    const u16* __restrict__ WT, int r15, int g4, f32x4 acc[4][4])
{
    #pragma unroll
    for (int kt = 0; kt < 2; ++kt) {
        f16x8 A[4], B[4];
        #pragma unroll
        for (int mt = 0; mt < 4; ++mt) {
            int row = mt*16 + r15;
            int col = (kt*32 + g4*8) ^ ((row & 7) << 3);
            A[mt] = *(const f16x8*)&strip[row*64 + col];
        }
        #pragma unroll
        for (int nt = 0; nt < 4; ++nt)
            B[nt] = *(const f16x8*)&WT[(nt*16 + r15)*64 + kt*32 + g4*8];
        #pragma unroll
        for (int mt = 0; mt < 4; ++mt) {
            #pragma unroll
            for (int nt = 0; nt < 4; ++nt)
                acc[mt][nt] = __builtin_amdgcn_mfma_f32_16x16x32_f16(
                    A[mt], B[nt], acc[mt][nt], 0, 0, 0);
        }
    }
}

__device__ __forceinline__ void act_store(u16* __restrict__ strip,
    const float* __restrict__ bias, int r15, int g4, f32x4 acc[4][4])
{
    float bn[4];
    #pragma unroll
    for (int nt = 0; nt < 4; ++nt) bn[nt] = bias[nt*16 + r15];
    #pragma unroll
    for (int mt = 0; mt < 4; ++mt) {
        #pragma unroll
        for (int r = 0; r < 4; ++r) {
            int row = mt*16 + g4*4 + r;
            int rsw = (row & 7) << 3;
            #pragma unroll
            for (int nt = 0; nt < 4; ++nt)
                strip[row*64 + ((nt*16 + r15) ^ rsw)] =
                    f2h(silu_f(acc[mt][nt][r] + bn[nt]));
        }
    }
}

// ---------------------------------------------------------------------------
// Table build: grid = 136 pairs x 4 theta-chunks. Block = 4 waves x 64 rows.
// Row idx = chunk*256 + tid; theta = 8*sinh(-UMAX + idx*H_U).
// Writes G (NOT *theta) as f16: T[pid][idx][0:64].
// ---------------------------------------------------------------------------
__global__ __launch_bounds__(256) void build_kernel(
    const float* __restrict__ W0, const float* __restrict__ base_tab,
    const u16* __restrict__ WT1, const u16* __restrict__ WT2,
    const u16* __restrict__ WT3,
    const float* __restrict__ b1, const float* __restrict__ b2,
    const float* __restrict__ b3,
    u16* __restrict__ T)
{
    __shared__ __align__(16) u16 act[256 * 64];   // 32 KB

    const int tid  = (int)threadIdx.x;
    const int lane = tid & 63;
    const int wv   = tid >> 6;
    const int r15  = lane & 15;
    const int g4   = lane >> 4;

    const int pid   = (int)blockIdx.x >> 2;
    const int chunk = (int)blockIdx.x & 3;
    // decode tri id -> (s, d), s <= d
    int s = 0, rem = pid;
    while (rem >= 16 - s) { rem -= 16 - s; ++s; }
    const int d = s + rem;

    const int idx = chunk * 256 + tid;              // theta grid index
    const float u  = fmaf((float)idx, H_U, -UMAX);
    const float eu = __expf(u);
    const float theta = 4.0f * (eu - __frcp_rn(eu)); // 8*sinh(u)

    u16* strip = act + wv * 4096;

    f32x4 accG[4][4];
    #pragma unroll
    for (int nt = 0; nt < 4; ++nt) {
        float bv = 2.0f * b3[nt*16 + r15];
        #pragma unroll
        for (int mt = 0; mt < 4; ++mt) accG[mt][nt] = {bv, bv, bv, bv};
    }

    #pragma unroll 1
    for (int m = 0; m < 2; ++m) {
        // layer 0 (one-hot collapsed)
        {
            const int p = m ? (d*16 + s) : (s*16 + d);
            const float4* bs4 = (const float4*)(base_tab + p*64);
            const float4* w04 = (const float4*)W0;
            const int rsw = (lane & 7) << 3;
            #pragma unroll
            for (int c = 0; c < 8; ++c) {
                float4 bl = bs4[2*c], bh = bs4[2*c+1];
                float4 wl = w04[2*c], wh = w04[2*c+1];
                u16x8 hv;
                hv[0] = f2h(silu_f(fmaf(theta, wl.x, bl.x)));
                hv[1] = f2h(silu_f(fmaf(theta, wl.y, bl.y)));
                hv[2] = f2h(silu_f(fmaf(theta, wl.z, bl.z)));
                hv[3] = f2h(silu_f(fmaf(theta, wl.w, bl.w)));
                hv[4] = f2h(silu_f(fmaf(theta, wh.x, bh.x)));
                hv[5] = f2h(silu_f(fmaf(theta, wh.y, bh.y)));
                hv[6] = f2h(silu_f(fmaf(theta, wh.z, bh.z)));
                hv[7] = f2h(silu_f(fmaf(theta, wh.w, bh.w)));
                *(u16x8*)&strip[lane*64 + ((c*8) ^ rsw)] = hv;
            }
        }
        // layer 1
        {
            f32x4 acc[4][4];
            #pragma unroll
            for (int mt = 0; mt < 4; ++mt)
                #pragma unroll
                for (int nt = 0; nt < 4; ++nt) acc[mt][nt] = {0.f,0.f,0.f,0.f};
            dense_mfma(strip, WT1, r15, g4, acc);
            act_store(strip, b1, r15, g4, acc);
        }
        // layer 2
        {
            f32x4 acc[4][4];
            #pragma unroll
            for (int mt = 0; mt < 4; ++mt)
                #pragma unroll
                for (int nt = 0; nt < 4; ++nt) acc[mt][nt] = {0.f,0.f,0.f,0.f};
            dense_mfma(strip, WT2, r15, g4, acc);
            act_store(strip, b2, r15, g4, acc);
        }
        // layer 3 -> persistent accG
        dense_mfma(strip, WT3, r15, g4, accG);
    }

    // stash G (f16) into act rows
    #pragma unroll
    for (int mt = 0; mt < 4; ++mt) {
        #pragma unroll
        for (int r = 0; r < 4; ++r) {
            int row = mt*16 + g4*4 + r;
            int rsw = (row & 7) << 3;
            #pragma unroll
            for (int nt = 0; nt < 4; ++nt)
                strip[row*64 + ((nt*16 + r15) ^ rsw)] = f2h(accG[mt][nt][r]);
        }
    }
    __syncthreads();

    // coalesced copy-out: thread tid owns act row tid -> T[pid][idx]
    u16* dst = T + ((size_t)pid * NT + (size_t)idx) * 64;
    const int rsw = (tid & 7) << 3;
    #pragma unroll
    for (int c = 0; c < 8; ++c)
        *(u16x8*)(dst + c*8) = *(const u16x8*)&act[tid*64 + ((c*8) ^ rsw)];
}

// ---------------------------------------------------------------------------
// Lookup + segmented reduction. Reduction is wave-per-segment, lane-per-feature:
// atomv[t] read is wave-uniform (LDS broadcast); red row read is 64 consecutive
// u16 = 2 lanes/bank (free); 64-lane atomicAdd on consecutive floats coalesces
// to 8x32B granules (R6's 8-wide variant hit 64 granules/instr: 111 MB writes).
// ---------------------------------------------------------------------------
__global__ __launch_bounds__(256) void lookup_kernel(
    const float4* __restrict__ rec, const u16* __restrict__ T,
    float* __restrict__ out)
{
    __shared__ __align__(16) u16 red[256 * 64];   // 32 KB, [t][j^((t&7)<<3)]
    __shared__ int atomv[256];
    __shared__ int seg_start[256];
    __shared__ int nseg;

    const int tid  = (int)threadIdx.x;
    const int lane = tid & 63;
    const int wv   = tid >> 6;
    const int i = (int)blockIdx.x * 256 + tid;
    const bool active = (i < N_ANGLES);
    const float4 rv = rec[active ? i : 0];

    const float theta = active ? rv.x : 0.0f;
    const int   pid   = __float_as_int(rv.y);
    const int   ca    = active ? __float_as_int(rv.z) : -1;

    if (tid == 0) nseg = 0;
    atomv[tid] = ca;

    // u = asinh(theta/8); t = (u+UMAX)/h_u; lerp rows i0, i0+1
    const float x  = theta * 0.125f;
    const float ax = fabsf(x);
    float uu = __logf(ax + __fsqrt_rn(fmaf(ax, ax, 1.0f)));
    uu = copysignf(uu, x);
    float tt = fminf(fmaxf(fmaf(uu, INV_HU, UMAX * INV_HU), 0.0f),
                     (float)NT - 1.001f);
    const int   i0 = (int)tt;
    const float fr = tt - (float)i0;

    const u16* __restrict__ r0 = T + ((size_t)pid * NT + (size_t)i0) * 64;
    const int rsw = (tid & 7) << 3;
    #pragma unroll
    for (int c = 0; c < 8; ++c) {
        u16x8 va = *(const u16x8*)(r0 + c*8);
        u16x8 vb = *(const u16x8*)(r0 + 64 + c*8);
        u16x8 o;
        #pragma unroll
        for (int q = 0; q < 8; ++q) {
            float ga = h2f(va[q]);
            float g  = fmaf(fr, h2f(vb[q]) - ga, ga);
            o[q] = f2h(g * theta);
        }
        *(u16x8*)&red[tid*64 + ((c*8) ^ rsw)] = o;
    }
    __syncthreads();

    if (active && (tid == 0 || atomv[tid] != atomv[tid-1]))
        seg_start[atomicAdd(&nseg, 1)] = tid;
    __syncthreads();

    // wave-per-segment, lane-per-feature
    const int NS = nseg;
    for (int s = wv; s < NS; s += 4) {
        const int st = seg_start[s];
        const int atom = atomv[st];
        float sum = 0.0f;
        for (int t = st; t < 256 && atomv[t] == atom; ++t)
            sum += h2f(red[t*64 + (lane ^ ((t & 7) << 3))]);
        atomicAdd(out + (size_t)atom * 64 + lane, sum);
    }
}

extern "C" void kernel_launch(void* const* d_in, const int* in_sizes, int n_in,
                              void* d_out, int out_size, void* d_ws, size_t ws_size,
                              hipStream_t stream) {
    const int*   species   = (const int*)  d_in[0];
    const int*   edge_dst  = (const int*)  d_in[1];
    const float* distances = (const float*)d_in[2];
    const float* sw        = (const float*)d_in[3];
    const float* vec       = (const float*)d_in[4];
    const int*   a_src     = (const int*)  d_in[5];
    const int*   a_dst     = (const int*)  d_in[6];
    const int*   a_ca      = (const int*)  d_in[7];
    const float* W0 = (const float*)d_in[8];
    const float* b0 = (const float*)d_in[9];
    const float* W1 = (const float*)d_in[10];
    const float* b1 = (const float*)d_in[11];
    const float* W2 = (const float*)d_in[12];
    const float* b2 = (const float*)d_in[13];
    const float* W3 = (const float*)d_in[14];
    const float* b3 = (const float*)d_in[15];
    float* out = (float*)d_out;

    // ws: Rij 25.6M | espec 6.4M | cnt | cursor | bsum | boff | rec 24M |
    //     WT1/2/3 | base_tab | T 17.8M   (~75 MB; int prefix = 1,700,392
    //     ints = multiple of 4 -> rec stays 16B-aligned)
    float4* Rij    = (float4*)d_ws;
    int*    espec  = (int*)(Rij + N_EDGES);
    int*    cnt    = espec + N_EDGES;
    int*    cursor = cnt + N_ATOMS;
    int*    bsum   = cursor + N_ATOMS;
    int*    boff   = bsum + SCAN_B;
    float4* rec    = (float4*)(boff + SCAN_B);
    u16*    WT1    = (u16*)(rec + N_ANGLES);
    u16*    WT2    = WT1 + 4096;
    u16*    WT3    = WT2 + 4096;
    float*  base_tab = (float*)(WT3 + 4096);
    u16*    T      = (u16*)(base_tab + 256*64);

    hipMemsetAsync(d_out, 0, (size_t)out_size * sizeof(float), stream);
    hipMemsetAsync(cnt, 0, (size_t)N_ATOMS * sizeof(int), stream);

    edge_kernel<<<(N_EDGES + 255) / 256, 256, 0, stream>>>(
        distances, sw, vec, edge_dst, species, Rij, espec);
    prep_kernel<<<(3*4096 + 256*64 + 255) / 256, 256, 0, stream>>>(
        W0, b0, W1, W2, W3, WT1, WT2, WT3, base_tab);
    hist_kernel<<<(N_ANGLES + 255) / 256, 256, 0, stream>>>(a_ca, cnt);
    scanA_kernel<<<SCAN_B, 256, 0, stream>>>(cnt, bsum);
    scanB_kernel<<<1, 256, 0, stream>>>(bsum, boff);
    scanC_kernel<<<SCAN_B, 256, 0, stream>>>(cnt, boff, cursor);
    scatter_kernel<<<(N_ANGLES + 255) / 256, 256, 0, stream>>>(
        a_src, a_dst, a_ca, Rij, espec, cursor, rec);
    build_kernel<<<136 * 4, 256, 0, stream>>>(
        W0, base_tab, WT1, WT2, WT3, b1, b2, b3, T);
    lookup_kernel<<<(N_ANGLES + 255) / 256, 256, 0, stream>>>(rec, T, out);
}

// Round 8
// 331.789 us; speedup vs baseline: 3.2254x; 1.2095x over previous
//
#include <hip/hip_runtime.h>

#define N_ATOMS   50000
#define N_EDGES   1600000
#define N_ANGLES  1500000
#define SCAN_B    196            // ceil(N_ATOMS/256)

// theta-table: theta = 8*sinh(u), u uniform on [-UMAX, UMAX], NT points.
#define NT      512
#define UMAX    4.852092f
#define H_U     0.01899253f      // 2*UMAX/(NT-1)
#define INV_HU  52.65766f        // (NT-1)/(2*UMAX)

typedef unsigned short u16;
typedef _Float16 f16x8 __attribute__((ext_vector_type(8)));
typedef _Float16 f16x4 __attribute__((ext_vector_type(4)));
typedef float    f32x4 __attribute__((ext_vector_type(4)));
typedef u16      u16x8 __attribute__((ext_vector_type(8)));

__device__ __forceinline__ float silu_f(float x) {
    return __fdividef(x, 1.0f + __expf(-x));
}
__device__ __forceinline__ u16 f2h(float x) {
    _Float16 h = (_Float16)x;
    return __builtin_bit_cast(u16, h);
}
__device__ __forceinline__ float h2f(u16 u) {
    return (float)__builtin_bit_cast(_Float16, u);
}

// ---------------------------------------------------------------------------
// Edge precompute: EC[e] = {f16x4 (s/d, s/d^2*vec), spec=species[edge_dst], pad}
// One 16B record = ONE random line per gather in scatter (was 2: Rij + espec).
// ---------------------------------------------------------------------------
__global__ __launch_bounds__(256) void edge_kernel(
    const float* __restrict__ distances, const float* __restrict__ sw,
    const float* __restrict__ vec, const int* __restrict__ edge_dst,
    const int* __restrict__ species, float4* __restrict__ EC)
{
    int e = (int)blockIdx.x * 256 + (int)threadIdx.x;
    if (e >= N_EDGES) return;
    const float d   = distances[e];
    const float s   = sw[e];
    const float inv = 1.0f / d;
    const float sij = s * inv;
    const float c   = sij * inv;
    f16x4 h;
    h[0] = (_Float16)sij;
    h[1] = (_Float16)(c * vec[3*e+0]);
    h[2] = (_Float16)(c * vec[3*e+1]);
    h[3] = (_Float16)(c * vec[3*e+2]);
    const float2 p = __builtin_bit_cast(float2, h);
    EC[e] = make_float4(p.x, p.y, __int_as_float(species[edge_dst[e]]), 0.0f);
}

// ---------------------------------------------------------------------------
// Prep: WTl[n][k] = f16(Wl[k][n]);  base_tab[s*16+d][j] = W0[1+s][j]+W0[17+d][j]+b0[j]
// ---------------------------------------------------------------------------
__global__ __launch_bounds__(256) void prep_kernel(
    const float* __restrict__ W0, const float* __restrict__ b0,
    const float* __restrict__ W1, const float* __restrict__ W2,
    const float* __restrict__ W3,
    u16* __restrict__ WT1, u16* __restrict__ WT2, u16* __restrict__ WT3,
    float* __restrict__ base_tab)
{
    int t = (int)blockIdx.x * 256 + (int)threadIdx.x;
    if (t < 3 * 4096) {
        int l = t >> 12, e = t & 4095, n = e >> 6, k = e & 63;
        const float* W = (l == 0) ? W1 : (l == 1) ? W2 : W3;
        u16* WT        = (l == 0) ? WT1 : (l == 1) ? WT2 : WT3;
        WT[n*64 + k] = f2h(W[k*64 + n]);
    }
    int u = t - 3 * 4096;
    if (u >= 0 && u < 256 * 64) {
        int sd = u >> 6, j = u & 63, s = sd >> 4, d = sd & 15;
        base_tab[u] = W0[(1+s)*64 + j] + W0[(17+d)*64 + j] + b0[j];
    }
}

// ---------------------------------------------------------------------------
// CSR build: histogram -> 3-stage parallel scan -> gather+scatter
// ---------------------------------------------------------------------------
__global__ __launch_bounds__(256) void hist_kernel(
    const int* __restrict__ a_ca, int* __restrict__ cnt)
{
    int i = (int)blockIdx.x * 256 + (int)threadIdx.x;
    if (i < N_ANGLES) atomicAdd(&cnt[a_ca[i]], 1);
}

__global__ __launch_bounds__(256) void scanA_kernel(
    const int* __restrict__ cnt, int* __restrict__ bsum)
{
    __shared__ int ws[4];
    const int t = (int)threadIdx.x;
    const int idx = (int)blockIdx.x * 256 + t;
    int v = (idx < N_ATOMS) ? cnt[idx] : 0;
    #pragma unroll
    for (int off = 32; off; off >>= 1) v += __shfl_down(v, off, 64);
    if ((t & 63) == 0) ws[t >> 6] = v;
    __syncthreads();
    if (t == 0) bsum[blockIdx.x] = ws[0] + ws[1] + ws[2] + ws[3];
}

__global__ __launch_bounds__(256) void scanB_kernel(
    const int* __restrict__ bsum, int* __restrict__ boff)
{
    __shared__ int sh[256];
    const int t = (int)threadIdx.x;
    int v = (t < SCAN_B) ? bsum[t] : 0;
    sh[t] = v;
    __syncthreads();
    for (int off = 1; off < 256; off <<= 1) {
        int u = (t >= off) ? sh[t - off] : 0;
        __syncthreads();
        sh[t] += u;
        __syncthreads();
    }
    if (t < SCAN_B) boff[t] = sh[t] - v;   // exclusive
}

__global__ __launch_bounds__(256) void scanC_kernel(
    const int* __restrict__ cnt, const int* __restrict__ boff,
    int* __restrict__ cursor)
{
    __shared__ int sh[256];
    const int t = (int)threadIdx.x;
    const int idx = (int)blockIdx.x * 256 + t;
    int v = (idx < N_ATOMS) ? cnt[idx] : 0;
    sh[t] = v;
    __syncthreads();
    for (int off = 1; off < 256; off <<= 1) {
        int u = (t >= off) ? sh[t - off] : 0;
        __syncthreads();
        sh[t] += u;
        __syncthreads();
    }
    if (idx < N_ATOMS) cursor[idx] = boff[blockIdx.x] + sh[t] - v;
}

// Writes atom-sorted 8B record per angle: {theta, (pid<<17)|ca}.
// tri id (s<=d canonical, G symmetric in (s,d)): pid = 16s - s(s-1)/2 + (d-s).
__global__ __launch_bounds__(256) void scatter_kernel(
    const int* __restrict__ a_src, const int* __restrict__ a_dst,
    const int* __restrict__ a_ca, const float4* __restrict__ EC,
    int* __restrict__ cursor, float2* __restrict__ rec)
{
    int i = (int)blockIdx.x * 256 + (int)threadIdx.x;
    if (i >= N_ANGLES) return;
    const int se = a_src[i], de = a_dst[i], ca = a_ca[i];
    const float4 Es = EC[se], Ed = EC[de];
    const f16x4 rs = __builtin_bit_cast(f16x4, make_float2(Es.x, Es.y));
    const f16x4 rd = __builtin_bit_cast(f16x4, make_float2(Ed.x, Ed.y));
    const float theta = (float)rs[0]*(float)rd[0] + (float)rs[1]*(float)rd[1]
                      + (float)rs[2]*(float)rd[2] + (float)rs[3]*(float)rd[3];
    const int s1 = __float_as_int(Es.z), s2 = __float_as_int(Ed.z);
    const int s = min(s1, s2), d = max(s1, s2);
    const int pid = s*16 - (s*(s-1))/2 + (d - s);
    const int pos = atomicAdd(&cursor[ca], 1);
    rec[pos] = make_float2(theta, __uint_as_float(((unsigned)pid << 17) | (unsigned)ca));
}

// ---------------------------------------------------------------------------
// MFMA helpers (static indexing; LDS tile u16 index = row*64 + (col^((row&7)<<3)))
// ---------------------------------------------------------------------------
__device__ __forceinline__ void dense_mfma(const u16* __restrict__ strip,
    const u16* __restrict__ WT, int r15, int g4, f32x4 acc[4][4])
{
    #pragma unroll
    for (int kt = 0; kt < 2; ++kt) {
        f16x8 A[4], B[4];
        #pragma unroll
        for (int mt = 0; mt < 4; ++mt) {
            int row = mt*16 + r15;
            int col = (kt*32 + g4*8) ^ ((row & 7) << 3);
            A[mt] = *(const f16x8*)&strip[row*64 + col];
        }
        #pragma unroll
        for (int nt = 0; nt < 4; ++nt)
            B[nt] = *(const f16x8*)&WT[(nt*16 + r15)*64 + kt*32 + g4*8];
        #pragma unroll
        for (int mt = 0; mt < 4; ++mt) {
            #pragma unroll
            for (int nt = 0; nt < 4; ++nt)
                acc[mt][nt] = __builtin_amdgcn_mfma_f32_16x16x32_f16(
                    A[mt], B[nt], acc[mt][nt], 0, 0, 0);
        }
    }
}

__device__ __forceinline__ void act_store(u16* __restrict__ strip,
    const float* __restrict__ bias, int r15, int g4, f32x4 acc[4][4])
{
    float bn[4];
    #pragma unroll
    for (int nt = 0; nt < 4; ++nt) bn[nt] = bias[nt*16 + r15];
    #pragma unroll
    for (int mt = 0; mt < 4; ++mt) {
        #pragma unroll
        for (int r = 0; r < 4; ++r) {
            int row = mt*16 + g4*4 + r;
            int rsw = (row & 7) << 3;
            #pragma unroll
            for (int nt = 0; nt < 4; ++nt)
                strip[row*64 + ((nt*16 + r15) ^ rsw)] =
                    f2h(silu_f(acc[mt][nt][r] + bn[nt]));
        }
    }
}

// ---------------------------------------------------------------------------
// Table build: grid = 136 pairs x 2 theta-chunks. Block = 4 waves x 64 rows.
// Row idx = chunk*256 + tid; theta = 8*sinh(-UMAX + idx*H_U).
// Writes G (NOT *theta) as f16: T[pid][idx][0:64].
// ---------------------------------------------------------------------------
__global__ __launch_bounds__(256) void build_kernel(
    const float* __restrict__ W0, const float* __restrict__ base_tab,
    const u16* __restrict__ WT1, const u16* __restrict__ WT2,
    const u16* __restrict__ WT3,
    const float* __restrict__ b1, const float* __restrict__ b2,
    const float* __restrict__ b3,
    u16* __restrict__ T)
{
    __shared__ __align__(16) u16 act[256 * 64];   // 32 KB

    const int tid  = (int)threadIdx.x;
    const int lane = tid & 63;
    const int wv   = tid >> 6;
    const int r15  = lane & 15;
    const int g4   = lane >> 4;

    const int pid   = (int)blockIdx.x >> 1;
    const int chunk = (int)blockIdx.x & 1;
    // decode tri id -> (s, d), s <= d
    int s = 0, rem = pid;
    while (rem >= 16 - s) { rem -= 16 - s; ++s; }
    const int d = s + rem;

    const int idx = chunk * 256 + tid;              // theta grid index
    const float u  = fmaf((float)idx, H_U, -UMAX);
    const float eu = __expf(u);
    const float theta = 4.0f * (eu - __frcp_rn(eu)); // 8*sinh(u)

    u16* strip = act + wv * 4096;

    f32x4 accG[4][4];
    #pragma unroll
    for (int nt = 0; nt < 4; ++nt) {
        float bv = 2.0f * b3[nt*16 + r15];
        #pragma unroll
        for (int mt = 0; mt < 4; ++mt) accG[mt][nt] = {bv, bv, bv, bv};
    }

    #pragma unroll 1
    for (int m = 0; m < 2; ++m) {
        // layer 0 (one-hot collapsed)
        {
            const int p = m ? (d*16 + s) : (s*16 + d);
            const float4* bs4 = (const float4*)(base_tab + p*64);
            const float4* w04 = (const float4*)W0;
            const int rsw = (lane & 7) << 3;
            #pragma unroll
            for (int c = 0; c < 8; ++c) {
                float4 bl = bs4[2*c], bh = bs4[2*c+1];
                float4 wl = w04[2*c], wh = w04[2*c+1];
                u16x8 hv;
                hv[0] = f2h(silu_f(fmaf(theta, wl.x, bl.x)));
                hv[1] = f2h(silu_f(fmaf(theta, wl.y, bl.y)));
                hv[2] = f2h(silu_f(fmaf(theta, wl.z, bl.z)));
                hv[3] = f2h(silu_f(fmaf(theta, wl.w, bl.w)));
                hv[4] = f2h(silu_f(fmaf(theta, wh.x, bh.x)));
                hv[5] = f2h(silu_f(fmaf(theta, wh.y, bh.y)));
                hv[6] = f2h(silu_f(fmaf(theta, wh.z, bh.z)));
                hv[7] = f2h(silu_f(fmaf(theta, wh.w, bh.w)));
                *(u16x8*)&strip[lane*64 + ((c*8) ^ rsw)] = hv;
            }
        }
        // layer 1
        {
            f32x4 acc[4][4];
            #pragma unroll
            for (int mt = 0; mt < 4; ++mt)
                #pragma unroll
                for (int nt = 0; nt < 4; ++nt) acc[mt][nt] = {0.f,0.f,0.f,0.f};
            dense_mfma(strip, WT1, r15, g4, acc);
            act_store(strip, b1, r15, g4, acc);
        }
        // layer 2
        {
            f32x4 acc[4][4];
            #pragma unroll
            for (int mt = 0; mt < 4; ++mt)
                #pragma unroll
                for (int nt = 0; nt < 4; ++nt) acc[mt][nt] = {0.f,0.f,0.f,0.f};
            dense_mfma(strip, WT2, r15, g4, acc);
            act_store(strip, b2, r15, g4, acc);
        }
        // layer 3 -> persistent accG
        dense_mfma(strip, WT3, r15, g4, accG);
    }

    // stash G (f16) into act rows
    #pragma unroll
    for (int mt = 0; mt < 4; ++mt) {
        #pragma unroll
        for (int r = 0; r < 4; ++r) {
            int row = mt*16 + g4*4 + r;
            int rsw = (row & 7) << 3;
            #pragma unroll
            for (int nt = 0; nt < 4; ++nt)
                strip[row*64 + ((nt*16 + r15) ^ rsw)] = f2h(accG[mt][nt][r]);
        }
    }
    __syncthreads();

    // coalesced copy-out: thread tid owns act row tid -> T[pid][idx]
    u16* dst = T + ((size_t)pid * NT + (size_t)idx) * 64;
    const int rsw = (tid & 7) << 3;
    #pragma unroll
    for (int c = 0; c < 8; ++c)
        *(u16x8*)(dst + c*8) = *(const u16x8*)&act[tid*64 + ((c*8) ^ rsw)];
}

// ---------------------------------------------------------------------------
// Lookup + segmented reduction. Wave-per-segment, lane-per-feature reduction
// (64-lane atomicAdd on consecutive floats coalesces to 8x32B granules).
// ---------------------------------------------------------------------------
__global__ __launch_bounds__(256) void lookup_kernel(
    const float2* __restrict__ rec, const u16* __restrict__ T,
    float* __restrict__ out)
{
    __shared__ __align__(16) u16 red[256 * 64];   // 32 KB, [t][j^((t&7)<<3)]
    __shared__ int atomv[256];
    __shared__ int seg_start[256];
    __shared__ int nseg;

    const int tid  = (int)threadIdx.x;
    const int lane = tid & 63;
    const int wv   = tid >> 6;
    const int i = (int)blockIdx.x * 256 + tid;
    const bool active = (i < N_ANGLES);
    const float2 rv = rec[active ? i : 0];

    const float    theta  = active ? rv.x : 0.0f;
    const unsigned packed = __float_as_uint(rv.y);
    const int      pid    = (int)(packed >> 17);
    const int      ca     = active ? (int)(packed & 0x1FFFFu) : -1;

    if (tid == 0) nseg = 0;
    atomv[tid] = ca;

    // u = asinh(theta/8); t = (u+UMAX)/h_u; lerp rows i0, i0+1
    const float x  = theta * 0.125f;
    const float ax = fabsf(x);
    float uu = __logf(ax + __fsqrt_rn(fmaf(ax, ax, 1.0f)));
    uu = copysignf(uu, x);
    float tt = fminf(fmaxf(fmaf(uu, INV_HU, UMAX * INV_HU), 0.0f),
                     (float)NT - 1.001f);
    const int   i0 = (int)tt;
    const float fr = tt - (float)i0;

    const u16* __restrict__ r0 = T + ((size_t)pid * NT + (size_t)i0) * 64;
    const int rsw = (tid & 7) << 3;
    #pragma unroll
    for (int c = 0; c < 8; ++c) {
        u16x8 va = *(const u16x8*)(r0 + c*8);
        u16x8 vb = *(const u16x8*)(r0 + 64 + c*8);
        u16x8 o;
        #pragma unroll
        for (int q = 0; q < 8; ++q) {
            float ga = h2f(va[q]);
            float g  = fmaf(fr, h2f(vb[q]) - ga, ga);
            o[q] = f2h(g * theta);
        }
        *(u16x8*)&red[tid*64 + ((c*8) ^ rsw)] = o;
    }
    __syncthreads();

    if (active && (tid == 0 || atomv[tid] != atomv[tid-1]))
        seg_start[atomicAdd(&nseg, 1)] = tid;
    __syncthreads();

    // wave-per-segment, lane-per-feature
    const int NS = nseg;
    for (int s = wv; s < NS; s += 4) {
        const int st = seg_start[s];
        const int atom = atomv[st];
        float sum = 0.0f;
        for (int t = st; t < 256 && atomv[t] == atom; ++t)
            sum += h2f(red[t*64 + (lane ^ ((t & 7) << 3))]);
        atomicAdd(out + (size_t)atom * 64 + lane, sum);
    }
}

extern "C" void kernel_launch(void* const* d_in, const int* in_sizes, int n_in,
                              void* d_out, int out_size, void* d_ws, size_t ws_size,
                              hipStream_t stream) {
    const int*   species   = (const int*)  d_in[0];
    const int*   edge_dst  = (const int*)  d_in[1];
    const float* distances = (const float*)d_in[2];
    const float* sw        = (const float*)d_in[3];
    const float* vec       = (const float*)d_in[4];
    const int*   a_src     = (const int*)  d_in[5];
    const int*   a_dst     = (const int*)  d_in[6];
    const int*   a_ca      = (const int*)  d_in[7];
    const float* W0 = (const float*)d_in[8];
    const float* b0 = (const float*)d_in[9];
    const float* W1 = (const float*)d_in[10];
    const float* b1 = (const float*)d_in[11];
    const float* W2 = (const float*)d_in[12];
    const float* b2 = (const float*)d_in[13];
    const float* W3 = (const float*)d_in[14];
    const float* b3 = (const float*)d_in[15];
    float* out = (float*)d_out;

    // ws: EC 25.6M | cnt | cursor | bsum | boff | rec 12M | WT1/2/3 | base_tab |
    //     T 8.9M  (~47 MB; all sub-arrays 16B-aligned by construction)
    float4* EC     = (float4*)d_ws;
    int*    cnt    = (int*)(EC + N_EDGES);
    int*    cursor = cnt + N_ATOMS;
    int*    bsum   = cursor + N_ATOMS;
    int*    boff   = bsum + SCAN_B;
    float2* rec    = (float2*)(boff + SCAN_B);
    u16*    WT1    = (u16*)(rec + N_ANGLES);
    u16*    WT2    = WT1 + 4096;
    u16*    WT3    = WT2 + 4096;
    float*  base_tab = (float*)(WT3 + 4096);
    u16*    T      = (u16*)(base_tab + 256*64);

    hipMemsetAsync(d_out, 0, (size_t)out_size * sizeof(float), stream);
    hipMemsetAsync(cnt, 0, (size_t)N_ATOMS * sizeof(int), stream);

    edge_kernel<<<(N_EDGES + 255) / 256, 256, 0, stream>>>(
        distances, sw, vec, edge_dst, species, EC);
    prep_kernel<<<(3*4096 + 256*64 + 255) / 256, 256, 0, stream>>>(
        W0, b0, W1, W2, W3, WT1, WT2, WT3, base_tab);
    hist_kernel<<<(N_ANGLES + 255) / 256, 256, 0, stream>>>(a_ca, cnt);
    scanA_kernel<<<SCAN_B, 256, 0, stream>>>(cnt, bsum);
    scanB_kernel<<<1, 256, 0, stream>>>(bsum, boff);
    scanC_kernel<<<SCAN_B, 256, 0, stream>>>(cnt, boff, cursor);
    scatter_kernel<<<(N_ANGLES + 255) / 256, 256, 0, stream>>>(
        a_src, a_dst, a_ca, EC, cursor, rec);
    build_kernel<<<136 * 2, 256, 0, stream>>>(
        W0, base_tab, WT1, WT2, WT3, b1, b2, b3, T);
    lookup_kernel<<<(N_ANGLES + 255) / 256, 256, 0, stream>>>(rec, T, out);
}